// Round 12
// baseline (199.623 us; speedup 1.0000x reference)
//
#include <hip/hip_runtime.h>
#include <hip/hip_bf16.h>

// Problem constants (fixed by setup_inputs)
constexpr int kH  = 112;
constexpr int kW  = 112;
constexpr int kC  = 64;
constexpr int kB  = 2;
constexpr int kHW = kH * kW;          // 12544
constexpr int kNP = kB * kHW;         // 25088 pixels

constexpr float kLog2e = 1.4426950408889634f;

// XCD swizzle (bijective, 1568 = 8*196). Both kernels band pixels identically:
// XCD k owns pixels [k*3136,(k+1)*3136) = 28 contiguous rows of one batch, so
// the g/s workspace is produced in the L2 of the XCD that consumes it.
__device__ __forceinline__ int xcd1568(int bid) { return (bid & 7) * 196 + (bid >> 3); }

// ---------------------------------------------------------------------------
// Kernel 0: transpose weights into workspace. w1t/w2t[c*64+o], w3t[c*64+o].
// ---------------------------------------------------------------------------
__global__ __launch_bounds__(256)
void prep(const float* __restrict__ w1, const float* __restrict__ w2,
          const float* __restrict__ w3, float* __restrict__ w1t,
          float* __restrict__ w2t, float* __restrict__ w3t)
{
    const int idx = blockIdx.x * 256 + threadIdx.x;   // [0, 16384)
    if (idx < 4096) {
        const int o = idx >> 6, c = idx & 63;
        w1t[c * 64 + o] = w1[idx];
    } else if (idx < 8192) {
        const int r = idx - 4096;
        const int o = r >> 6, c = r & 63;
        w2t[c * 64 + o] = w2[r];
    } else {
        const int r = idx - 8192;                     // [0, 8192)
        const int o = r >> 7, c = r & 127;
        w3t[c * 64 + o] = w3[r];
    }
}

// ---------------------------------------------------------------------------
// Kernel 1: g = w1 @ f_guide + b1 ; s = w2 @ f_source + b2  (per-pixel 1x1)
// 16 lanes/pixel (team 0: g-conv, team 1: s-conv; j owns 8 out channels).
// Inputs LDS-staged coalesced; weights read straight from pre-transposed
// w1t/w2t (identical addresses across pixel groups -> L1-dedup, no LDS
// staging / no 32KB-per-block copy). Output pixel-major (p,64) fp32.
// ---------------------------------------------------------------------------
__global__ __launch_bounds__(256, 6)
void conv_gs(const float* __restrict__ fg, const float* __restrict__ fs,
             const float* __restrict__ w1t, const float* __restrict__ b1,
             const float* __restrict__ w2t, const float* __restrict__ b2,
             float* __restrict__ gw, float* __restrict__ sw)
{
    __shared__ float xls[2][64 * 17];   // xls[t][c*17+px], padded stride

    const int d   = xcd1568(blockIdx.x);
    const int p0  = d * 16;
    const int b   = p0 / kHW;          // blocks never straddle batches (16|12544)
    const int pb0 = p0 - b * kHW;

    // Stage 16 pixels x 64 ch x {fg,fs}: lanes sweep px -> coalesced.
    for (int idx = threadIdx.x; idx < 2048; idx += 256) {
        const int t  = idx >> 10;
        const int c  = (idx >> 4) & 63;
        const int px = idx & 15;
        xls[t][c * 17 + px] = (t ? fs : fg)[(size_t)(b * kC + c) * kHW + pb0 + px];
    }
    __syncthreads();

    const int grp = threadIdx.x >> 4;  // pixel within tile
    const int i   = threadIdx.x & 15;
    const int t   = i >> 3;            // 0: guide-conv, 1: source-conv
    const int j   = i & 7;             // owns output channels 8j..8j+7
    const int p   = p0 + grp;

    float x[8];
#pragma unroll
    for (int cc = 0; cc < 8; ++cc)
        x[cc] = xls[t][(8 * j + cc) * 17 + grp];

    const float* bias = t ? b2 : b1;
    const float* wb   = t ? w2t : w1t;

    float a[8];
    {
        const float4 bb0  = *(const float4*)(bias + 8 * j);
        const float4 bb1v = *(const float4*)(bias + 8 * j + 4);
        a[0] = bb0.x;  a[1] = bb0.y;  a[2] = bb0.z;  a[3] = bb0.w;
        a[4] = bb1v.x; a[5] = bb1v.y; a[6] = bb1v.z; a[7] = bb1v.w;
    }

    for (int c0 = 0; c0 < 64; c0 += 8) {
        const int sl = c0 >> 3;
#pragma unroll
        for (int k = 0; k < 8; ++k) {
            const float xc = __shfl(x[k], sl, 8);     // broadcast within team
            const float* wr = wb + (c0 + k) * 64 + 8 * j;
            const float4 w0 = *(const float4*)(wr);
            const float4 w1v = *(const float4*)(wr + 4);
            a[0] = fmaf(w0.x, xc, a[0]);  a[1] = fmaf(w0.y, xc, a[1]);
            a[2] = fmaf(w0.z, xc, a[2]);  a[3] = fmaf(w0.w, xc, a[3]);
            a[4] = fmaf(w1v.x, xc, a[4]); a[5] = fmaf(w1v.y, xc, a[5]);
            a[6] = fmaf(w1v.z, xc, a[6]); a[7] = fmaf(w1v.w, xc, a[7]);
        }
    }
    float* dst = (t ? sw : gw) + (size_t)p * 64 + 8 * j;
    *(float4*)(dst)     = make_float4(a[0], a[1], a[2], a[3]);
    *(float4*)(dst + 4) = make_float4(a[4], a[5], a[6], a[7]);
}

// ---------------------------------------------------------------------------
// Kernel 2: fused 11x11 s->g attention, 5x5 g->s attention, 1x1 fusion conv.
// Block = 8x2 pixel tile, 512 threads, 32 lanes/pixel (4 teams of 8).
// Neighborhood halos are LDS-staged with zeros for OOB -> the inner loops are
// GUARD-free and fed by ds_read_b128. Pixel stride padded to 68 floats
// (272B) so reads/writes spread across banks. s-halo 18x12 (58.8KB),
// g-halo 12x6 (19.6KB, reuses the same buffer).
// No-max softmax: scores bounded, exp2 can't overflow; staged zero vectors
// give score 0 -> weight 1 in the denominator (matches zero-padded unfold).
// ---------------------------------------------------------------------------
constexpr int kSP = 68;                 // LDS pixel stride (floats)

__global__ __launch_bounds__(512, 4)
void attn_fuse(const float* __restrict__ gw, const float* __restrict__ sw,
               const float* __restrict__ w3t, const float* __restrict__ b3,
               float* __restrict__ out)
{
    __shared__ float tile[216 * kSP];   // 58752 B

    const int d    = xcd1568(blockIdx.x);
    const int b    = d / 784;
    const int r    = d - b * 784;
    const int band = r / 14;            // 56 bands of 2 rows per batch
    const int tw   = r - band * 14;     // 14 tiles of 8 wide
    const int h0   = band * 2;
    const int w0   = tw * 8;

    const int grp = threadIdx.x >> 5;   // pixel 0..15
    const int i   = threadIdx.x & 31;
    const int t   = i >> 3;             // team 0..3
    const int j   = i & 7;              // owns channels 8j..8j+7
    const int ly  = grp >> 3;           // 0..1
    const int lx  = grp & 7;            // 0..7
    const int h   = h0 + ly;
    const int w   = w0 + lx;
    const int p   = (b * kH + h) * kW + w;

    const float* gb = gw + (size_t)b * kHW * 64;
    const float* sb = sw + (size_t)b * kHW * 64;

    // ---- stage s-halo: 18 cols x 12 rows, zeros outside the image
    for (int idx = threadIdx.x; idx < 216 * 64; idx += 512) {
        const int pix = idx >> 6, c = idx & 63;
        const int py = pix / 18, px = pix - py * 18;
        const int gh = h0 - 5 + py, gx = w0 - 5 + px;
        const bool v = ((unsigned)gh < (unsigned)kH) & ((unsigned)gx < (unsigned)kW);
        tile[pix * kSP + c] = v ? sb[(size_t)(gh * kW + gx) * 64 + c] : 0.f;
    }
    __syncthreads();

    // ---- phase 1: source -> guide (11x11 over staged s, query = g pixel)
    float fs2g[8];
    {
        float qs[8];
        const float4 g0 = *(const float4*)(gw + (size_t)p * 64 + 8 * j);
        const float4 g1 = *(const float4*)(gw + (size_t)p * 64 + 8 * j + 4);
        qs[0] = g0.x * kLog2e; qs[1] = g0.y * kLog2e;
        qs[2] = g0.z * kLog2e; qs[3] = g0.w * kLog2e;
        qs[4] = g1.x * kLog2e; qs[5] = g1.y * kLog2e;
        qs[6] = g1.z * kLog2e; qs[7] = g1.w * kLog2e;

        float acc[8] = {0.f, 0.f, 0.f, 0.f, 0.f, 0.f, 0.f, 0.f};
        float l = 0.f;
        for (int n = t; n < 121; n += 4) {
            const int q = n / 11, rr = n - q * 11;
            const float* np = &tile[((ly + q) * 18 + lx + rr) * kSP + 8 * j];
            const float4 n0 = *(const float4*)(np);
            const float4 n1 = *(const float4*)(np + 4);
            float dd = n0.x * qs[0];
            dd = fmaf(n0.y, qs[1], dd);
            dd = fmaf(n0.z, qs[2], dd);
            dd = fmaf(n0.w, qs[3], dd);
            dd = fmaf(n1.x, qs[4], dd);
            dd = fmaf(n1.y, qs[5], dd);
            dd = fmaf(n1.z, qs[6], dd);
            dd = fmaf(n1.w, qs[7], dd);
            dd += __shfl_xor(dd, 1);
            dd += __shfl_xor(dd, 2);
            dd += __shfl_xor(dd, 4);
            const float pe = __builtin_amdgcn_exp2f(dd);
            l += pe;
            acc[0] = fmaf(pe, n0.x, acc[0]);
            acc[1] = fmaf(pe, n0.y, acc[1]);
            acc[2] = fmaf(pe, n0.z, acc[2]);
            acc[3] = fmaf(pe, n0.w, acc[3]);
            acc[4] = fmaf(pe, n1.x, acc[4]);
            acc[5] = fmaf(pe, n1.y, acc[5]);
            acc[6] = fmaf(pe, n1.z, acc[6]);
            acc[7] = fmaf(pe, n1.w, acc[7]);
        }
        // merge 4 team partials (butterfly over lanes 8,16)
        l += __shfl_xor(l, 8);
        l += __shfl_xor(l, 16);
#pragma unroll
        for (int k = 0; k < 8; ++k) {
            acc[k] += __shfl_xor(acc[k], 8);
            acc[k] += __shfl_xor(acc[k], 16);
        }
        const float inv = 1.0f / l;
#pragma unroll
        for (int k = 0; k < 8; ++k) fs2g[k] = acc[k] * inv;
    }
    __syncthreads();                    // all phase-1 reads done

    // ---- stage g-halo: 12 cols x 6 rows (reuses the buffer)
    for (int idx = threadIdx.x; idx < 72 * 64; idx += 512) {
        const int pix = idx >> 6, c = idx & 63;
        const int py = pix / 12, px = pix - py * 12;
        const int gh = h0 - 2 + py, gx = w0 - 2 + px;
        const bool v = ((unsigned)gh < (unsigned)kH) & ((unsigned)gx < (unsigned)kW);
        tile[pix * kSP + c] = v ? gb[(size_t)(gh * kW + gx) * 64 + c] : 0.f;
    }
    __syncthreads();

    // ---- phase 2: guide -> source (5x5 over staged g, query = s pixel)
    float fg2s[8];
    {
        float qs[8];
        const float4 s0 = *(const float4*)(sw + (size_t)p * 64 + 8 * j);
        const float4 s1 = *(const float4*)(sw + (size_t)p * 64 + 8 * j + 4);
        qs[0] = s0.x * kLog2e; qs[1] = s0.y * kLog2e;
        qs[2] = s0.z * kLog2e; qs[3] = s0.w * kLog2e;
        qs[4] = s1.x * kLog2e; qs[5] = s1.y * kLog2e;
        qs[6] = s1.z * kLog2e; qs[7] = s1.w * kLog2e;

        float acc[8] = {0.f, 0.f, 0.f, 0.f, 0.f, 0.f, 0.f, 0.f};
        float l = 0.f;
        for (int n = t; n < 25; n += 4) {
            const int q = n / 5, rr = n - q * 5;
            const float* np = &tile[((ly + q) * 12 + lx + rr) * kSP + 8 * j];
            const float4 n0 = *(const float4*)(np);
            const float4 n1 = *(const float4*)(np + 4);
            float dd = n0.x * qs[0];
            dd = fmaf(n0.y, qs[1], dd);
            dd = fmaf(n0.z, qs[2], dd);
            dd = fmaf(n0.w, qs[3], dd);
            dd = fmaf(n1.x, qs[4], dd);
            dd = fmaf(n1.y, qs[5], dd);
            dd = fmaf(n1.z, qs[6], dd);
            dd = fmaf(n1.w, qs[7], dd);
            dd += __shfl_xor(dd, 1);
            dd += __shfl_xor(dd, 2);
            dd += __shfl_xor(dd, 4);
            const float pe = __builtin_amdgcn_exp2f(dd);
            l += pe;
            acc[0] = fmaf(pe, n0.x, acc[0]);
            acc[1] = fmaf(pe, n0.y, acc[1]);
            acc[2] = fmaf(pe, n0.z, acc[2]);
            acc[3] = fmaf(pe, n0.w, acc[3]);
            acc[4] = fmaf(pe, n1.x, acc[4]);
            acc[5] = fmaf(pe, n1.y, acc[5]);
            acc[6] = fmaf(pe, n1.z, acc[6]);
            acc[7] = fmaf(pe, n1.w, acc[7]);
        }
        l += __shfl_xor(l, 8);
        l += __shfl_xor(l, 16);
#pragma unroll
        for (int k = 0; k < 8; ++k) {
            acc[k] += __shfl_xor(acc[k], 8);
            acc[k] += __shfl_xor(acc[k], 16);
        }
        const float inv = 1.0f / l;
#pragma unroll
        for (int k = 0; k < 8; ++k) fg2s[k] = acc[k] * inv;
    }

    // ---- fusion: out[o] = sum_{c<128} w3t[c][o] * x[c] + b3[o],
    // x = [fs2g; fg2s]. Team t owns w3t rows t*32..t*32+31; butterfly-merge.
    float xsrc[8];
#pragma unroll
    for (int k = 0; k < 8; ++k) xsrc[k] = (t < 2) ? fs2g[k] : fg2s[k];

    float fo[8] = {0.f, 0.f, 0.f, 0.f, 0.f, 0.f, 0.f, 0.f};
    for (int m0 = 0; m0 < 32; m0 += 8) {
        const int srcl = (((t & 1) << 5) + m0) >> 3;        // broadcast lane
        const float* wrow = w3t + (size_t)(t * 32 + m0) * 64 + 8 * j;
#pragma unroll
        for (int mm = 0; mm < 8; ++mm) {
            const float xc = __shfl(xsrc[mm], srcl, 8);
            const float4 w0 = *(const float4*)(wrow + mm * 64);
            const float4 w1v = *(const float4*)(wrow + mm * 64 + 4);
            fo[0] = fmaf(w0.x, xc, fo[0]);  fo[1] = fmaf(w0.y, xc, fo[1]);
            fo[2] = fmaf(w0.z, xc, fo[2]);  fo[3] = fmaf(w0.w, xc, fo[3]);
            fo[4] = fmaf(w1v.x, xc, fo[4]); fo[5] = fmaf(w1v.y, xc, fo[5]);
            fo[6] = fmaf(w1v.z, xc, fo[6]); fo[7] = fmaf(w1v.w, xc, fo[7]);
        }
    }
#pragma unroll
    for (int k = 0; k < 8; ++k) {
        fo[k] += __shfl_xor(fo[k], 8);
        fo[k] += __shfl_xor(fo[k], 16);
    }

    // Store: team t writes channels 8j+2t and 8j+2t+1 (static reg indices).
    const float e0 = (t & 2) ? fo[4] : fo[0];
    const float e1 = (t & 2) ? fo[5] : fo[1];
    const float e2 = (t & 2) ? fo[6] : fo[2];
    const float e3 = (t & 2) ? fo[7] : fo[3];
    const float o0 = (t & 1) ? e2 : e0;
    const float o1 = (t & 1) ? e3 : e1;
    const int c0 = 8 * j + 2 * t;
    const size_t a0 = ((size_t)(b * kC + c0) * kH + h) * kW + w;
    out[a0]       = o0 + b3[c0];
    out[a0 + kHW] = o1 + b3[c0 + 1];
}

extern "C" void kernel_launch(void* const* d_in, const int* in_sizes, int n_in,
                              void* d_out, int out_size, void* d_ws, size_t ws_size,
                              hipStream_t stream)
{
    const float* fg = (const float*)d_in[0];
    const float* fs = (const float*)d_in[1];
    const float* w1 = (const float*)d_in[2];
    const float* b1 = (const float*)d_in[3];
    const float* w2 = (const float*)d_in[4];
    const float* b2 = (const float*)d_in[5];
    const float* w3 = (const float*)d_in[6];
    const float* b3 = (const float*)d_in[7];
    float* outp = (float*)d_out;

    float* gws = (float*)d_ws;                 // (p,64) fp32, 6.4 MB
    float* sws = gws + (size_t)kNP * 64;       // (p,64) fp32, 6.4 MB
    float* w3t = sws + (size_t)kNP * 64;       // 128x64 fp32, 32 KB
    float* w1t = w3t + 128 * 64;               // 64x64 fp32, 16 KB
    float* w2t = w1t + 64 * 64;                // 64x64 fp32, 16 KB

    prep<<<64, 256, 0, stream>>>(w1, w2, w3, w1t, w2t, w3t);
    conv_gs<<<1568, 256, 0, stream>>>(fg, fs, w1t, b1, w2t, b2, gws, sws);
    attn_fuse<<<1568, 512, 0, stream>>>(gws, sws, w3t, b3, outp);
}